// Round 2
// baseline (731.113 us; speedup 1.0000x reference)
//
#include <hip/hip_runtime.h>

// MoE switch layer: B=8, N=2048, D=1024, E=8, DFF=4096, CAP=320
#define Bq 8
#define Nq 2048
#define Dq 1024
#define Eq 8
#define DFFq 4096
#define CAPq 320
#define Mq (Bq * CAPq)   // 2560 rows per expert
#define Tq (Bq * Nq)     // 16384 tokens

typedef __attribute__((ext_vector_type(8))) short bf16x8;
typedef __attribute__((ext_vector_type(4))) float f32x4;

static __device__ __forceinline__ unsigned short f2bf(float f) {
    union { float f; unsigned u; } v;
    v.f = f;
    unsigned r = v.u + 0x7fffu + ((v.u >> 16) & 1u);   // RNE
    return (unsigned short)(r >> 16);
}

static __device__ __forceinline__ void gload_lds16(const void* g, void* l) {
    __builtin_amdgcn_global_load_lds(
        (const __attribute__((address_space(1))) unsigned int*)g,
        (__attribute__((address_space(3))) unsigned int*)l, 16, 0, 0);
}

// ---------------- routing: logits -> softmax -> argmax/gate ----------------
__global__ __launch_bounds__(256) void route_kernel(
    const float* __restrict__ tok, const float* __restrict__ Wg,
    int* __restrict__ eidx, float* __restrict__ gate)
{
    int wv = threadIdx.x >> 6, lane = threadIdx.x & 63;
    int t = blockIdx.x * 4 + wv;
    const float* tp = tok + (size_t)t * Dq;
    float acc[8] = {0.f,0.f,0.f,0.f,0.f,0.f,0.f,0.f};
    for (int it = 0; it < Dq / 64; ++it) {
        int d = it * 64 + lane;
        float x = tp[d];
        const float4* w = (const float4*)(Wg + (size_t)d * 8);
        float4 w0 = w[0], w1 = w[1];
        acc[0] += x * w0.x; acc[1] += x * w0.y; acc[2] += x * w0.z; acc[3] += x * w0.w;
        acc[4] += x * w1.x; acc[5] += x * w1.y; acc[6] += x * w1.z; acc[7] += x * w1.w;
    }
#pragma unroll
    for (int e = 0; e < 8; ++e)
#pragma unroll
        for (int off = 32; off; off >>= 1)
            acc[e] += __shfl_xor(acc[e], off, 64);
    if (lane == 0) {
        float m = acc[0]; int bi = 0;
#pragma unroll
        for (int e = 1; e < 8; ++e) if (acc[e] > m) { m = acc[e]; bi = e; }
        float s = 0.f;
#pragma unroll
        for (int e = 0; e < 8; ++e) s += expf(acc[e] - m);
        eidx[t] = bi;
        gate[t] = 1.0f / s;   // max prob
    }
}

// ------------- slot assignment: cumsum-order scan per (b,e) ----------------
__global__ __launch_bounds__(64) void slot_kernel(
    const int* __restrict__ eidx, int* __restrict__ tfs)
{
    int b = blockIdx.x >> 3, e = blockIdx.x & 7;
    int lane = threadIdx.x;
    const int* ip = eidx + (size_t)b * Nq;
    int base = (e * Bq + b) * CAPq;
    int cnt = 0;
    for (int it = 0; it < Nq / 64; ++it) {
        int n = it * 64 + lane;
        bool my = (ip[n] == e);
        unsigned long long mask = __ballot(my);
        if (my) {
            int pos = cnt + __popcll(mask & ((1ull << lane) - 1ull));
            if (pos < CAPq) tfs[base + pos] = b * Nq + n;
        }
        cnt += __popcll(mask);
    }
}

// ------------- dispatch: gather token rows -> bf16 expert buffers ----------
__global__ __launch_bounds__(128) void dispatch_kernel(
    const float* __restrict__ tok, const int* __restrict__ tfs,
    unsigned short* __restrict__ X)
{
    int r = blockIdx.x;          // 0 .. E*B*CAP-1
    int t = tfs[r];
    int d0 = threadIdx.x * 8;
    unsigned short o[8];
    if (t < 0) {
#pragma unroll
        for (int k = 0; k < 8; ++k) o[k] = 0;
    } else {
        const float4* p = (const float4*)(tok + (size_t)t * Dq + d0);
        float4 a = p[0], b = p[1];
        o[0]=f2bf(a.x); o[1]=f2bf(a.y); o[2]=f2bf(a.z); o[3]=f2bf(a.w);
        o[4]=f2bf(b.x); o[5]=f2bf(b.y); o[6]=f2bf(b.z); o[7]=f2bf(b.w);
    }
    *(uint4*)(X + (size_t)r * Dq + d0) = *(const uint4*)o;
}

// ------- weight transpose+convert: in [E][R][C] f32 -> out [E][C][R] bf16 --
__global__ __launch_bounds__(256) void transpose_cvt(
    const float* __restrict__ in, unsigned short* __restrict__ out,
    int R, int C)
{
    __shared__ float tile[32][33];
    int e = blockIdx.z;
    int c0 = blockIdx.x * 32, r0 = blockIdx.y * 32;
    int tx = threadIdx.x & 31, ty = threadIdx.x >> 5;
    const float* ip = in + (size_t)e * R * C;
#pragma unroll
    for (int rr = 0; rr < 4; ++rr)
        tile[ty + rr * 8][tx] = ip[(size_t)(r0 + ty + rr * 8) * C + c0 + tx];
    __syncthreads();
    unsigned short* op = out + (size_t)e * R * C;
#pragma unroll
    for (int rr = 0; rr < 4; ++rr)
        op[(size_t)(c0 + ty + rr * 8) * R + r0 + tx] = f2bf(tile[tx][ty + rr * 8]);
}

// ---------------- pipelined NT GEMM: C[M][N] = A[M][K] * Bt[N][K]^T --------
// BM=256, BN=128, BK=64, 512 threads (8 waves = 4M x 2N), 3-deep LDS pipeline,
// counted vmcnt(6) (tile t+2 staged while computing tile t).
// MODE 0: H = relu(C) as bf16.  MODE 1: scatter rows to Out with gate.
template <int MODE, int Ndim, int Kdim>
__global__ __launch_bounds__(512) void gemm3(
    const unsigned short* __restrict__ A,   // [E][M][K] bf16
    const unsigned short* __restrict__ Bt,  // [E][N][K] bf16
    unsigned short* __restrict__ Hout,      // [E][M][N] bf16  (MODE 0)
    float* __restrict__ Out,                // [T][D] f32      (MODE 1)
    const int* __restrict__ tfs,            // [E][M]
    const float* __restrict__ gate)         // [T]
{
    constexpr int NT  = Kdim / 64;
    constexpr int NTB = Ndim / 128;
    constexpr int MT  = Mq / 256;          // 10
    constexpr int NWG = MT * NTB * Eq;     // divisible by 8 for both GEMMs

    __shared__ __align__(16) unsigned short As[3 * 256 * 64];  // 96 KiB
    __shared__ __align__(16) unsigned short Bs[3 * 128 * 64];  // 48 KiB
    __shared__ int   t_lds[256];
    __shared__ float g_lds[256];

    // XCD-aware bijective swizzle (NWG % 8 == 0)
    int flat = blockIdx.x;
    int wg = (flat & 7) * (NWG / 8) + (flat >> 3);
    int e   = wg / (MT * NTB);
    int rem = wg - e * (MT * NTB);
    int mb = rem / NTB, nb = rem - mb * NTB;
    int m0 = mb * 256, n0 = nb * 128;

    const unsigned short* Ae = A  + (size_t)e * Mq * Kdim + (size_t)m0 * Kdim;
    const unsigned short* Be = Bt + (size_t)e * Ndim * Kdim + (size_t)n0 * Kdim;

    const int tid = threadIdx.x;
    if (MODE == 1 && tid < 256) {
        int t = tfs[e * Mq + m0 + tid];
        t_lds[tid] = t;
        g_lds[tid] = (t >= 0) ? gate[t] : 0.f;
    }

    const int lane = tid & 63;
    const int wv = tid >> 6;
    const int wr = wv >> 1, wc = wv & 1;     // 4M x 2N waves, per-wave 64x64
    const int lrow = lane & 15;
    const int lk = lane >> 4;
    const int swz = (lrow & 7) << 4;

    // staging decode (constant per thread)
    const int srow = tid >> 3;                                     // 0..63
    const int sk   = ((tid & 7) << 4) ^ (((tid >> 3) & 7) << 4);   // pre-swizzled src byte
    const int wbase = wv << 10;                                    // wave-uniform LDS dest

    const char* gAb = (const char*)Ae + (size_t)srow * Kdim * 2 + sk;
    const char* gBb = (const char*)Be + (size_t)srow * Kdim * 2 + sk;

    #define STAGE_A(kt, buf)                                                    \
        {   const char* _g = gAb + (size_t)(kt) * 2;                            \
            char* _l = (char*)As + (buf) * 32768 + wbase;                       \
            gload_lds16(_g,                         _l);                        \
            gload_lds16(_g + (size_t) 64 * Kdim * 2, _l + 8192);                \
            gload_lds16(_g + (size_t)128 * Kdim * 2, _l + 16384);               \
            gload_lds16(_g + (size_t)192 * Kdim * 2, _l + 24576);  }
    #define STAGE_B(kt, buf)                                                    \
        {   const char* _g = gBb + (size_t)(kt) * 2;                            \
            char* _l = (char*)Bs + (buf) * 16384 + wbase;                       \
            gload_lds16(_g,                         _l);                        \
            gload_lds16(_g + (size_t) 64 * Kdim * 2, _l + 8192);  }

    f32x4 acc[4][4] = {};

    // prologue: stage tiles 0 and 1
    STAGE_A(0, 0);  STAGE_B(0, 0);
    STAGE_A(64, 1); STAGE_B(64, 1);
    asm volatile("s_waitcnt lgkmcnt(0)");     // publish t_lds/g_lds writes
    asm volatile("s_waitcnt vmcnt(6)");       // tile 0 resident
    __builtin_amdgcn_s_barrier();
    __builtin_amdgcn_sched_barrier(0);

    int cur = 0;
    for (int t = 0; t < NT; ++t) {
        const char* pa = (const char*)As + cur * 32768;
        const char* pb = (const char*)Bs + cur * 16384;
        int sbuf = cur + 2; if (sbuf >= 3) sbuf -= 3;
        const int kt2 = (t + 2) * 64;
        const bool st = (t + 2) < NT;

        // ---- phase 1: A frags + B cols 0..31, stage next A ----
        if (st) STAGE_A(kt2, sbuf);
        bf16x8 af[4][2], bf0[2][2];
#pragma unroll
        for (int i = 0; i < 4; ++i)
#pragma unroll
            for (int kk = 0; kk < 2; ++kk)
                af[i][kk] = *(const bf16x8*)(pa + (wr * 64 + i * 16 + lrow) * 128
                                               + ((kk * 64 + lk * 16) ^ swz));
#pragma unroll
        for (int j = 0; j < 2; ++j)
#pragma unroll
            for (int kk = 0; kk < 2; ++kk)
                bf0[j][kk] = *(const bf16x8*)(pb + (wc * 64 + j * 16 + lrow) * 128
                                                + ((kk * 64 + lk * 16) ^ swz));
        __builtin_amdgcn_s_setprio(1);
#pragma unroll
        for (int i = 0; i < 4; ++i)
#pragma unroll
            for (int j = 0; j < 2; ++j)
#pragma unroll
                for (int kk = 0; kk < 2; ++kk)
                    acc[i][j] = __builtin_amdgcn_mfma_f32_16x16x32_bf16(
                        af[i][kk], bf0[j][kk], acc[i][j], 0, 0, 0);
        __builtin_amdgcn_s_setprio(0);

        // ---- phase 2: B cols 32..63, stage next B ----
        if (st) STAGE_B(kt2, sbuf);
        bf16x8 bf1[2][2];
#pragma unroll
        for (int j = 0; j < 2; ++j)
#pragma unroll
            for (int kk = 0; kk < 2; ++kk)
                bf1[j][kk] = *(const bf16x8*)(pb + (wc * 64 + (j + 2) * 16 + lrow) * 128
                                                + ((kk * 64 + lk * 16) ^ swz));
        __builtin_amdgcn_s_setprio(1);
#pragma unroll
        for (int i = 0; i < 4; ++i)
#pragma unroll
            for (int j = 0; j < 2; ++j)
#pragma unroll
                for (int kk = 0; kk < 2; ++kk)
                    acc[i][j + 2] = __builtin_amdgcn_mfma_f32_16x16x32_bf16(
                        af[i][kk], bf1[j][kk], acc[i][j + 2], 0, 0, 0);
        __builtin_amdgcn_s_setprio(0);

        // ---- counted wait: tile t+1 must be resident for next iter ----
        if (st)                 asm volatile("s_waitcnt vmcnt(6)");
        else if (t + 1 < NT)    asm volatile("s_waitcnt vmcnt(0)");
        if (t + 1 < NT) {
            __builtin_amdgcn_s_barrier();
            __builtin_amdgcn_sched_barrier(0);
        }
        cur = cur + 1; if (cur == 3) cur = 0;
    }

    if (MODE == 0) {
        unsigned short* Hp = Hout + (size_t)e * Mq * Ndim;
#pragma unroll
        for (int i = 0; i < 4; ++i) {
            int r0 = m0 + wr * 64 + i * 16 + lk * 4;
#pragma unroll
            for (int j = 0; j < 4; ++j) {
                int col = n0 + wc * 64 + j * 16 + lrow;
#pragma unroll
                for (int r = 0; r < 4; ++r)
                    Hp[(size_t)(r0 + r) * Ndim + col] = f2bf(fmaxf(acc[i][j][r], 0.f));
            }
        }
    } else {
#pragma unroll
        for (int i = 0; i < 4; ++i) {
            int rl = wr * 64 + i * 16 + lk * 4;
#pragma unroll
            for (int r = 0; r < 4; ++r) {
                int tt = t_lds[rl + r];
                if (tt < 0) continue;
                float g = g_lds[rl + r];
#pragma unroll
                for (int j = 0; j < 4; ++j) {
                    int col = n0 + wc * 64 + j * 16 + lrow;
                    Out[(size_t)tt * Dq + col] = g * acc[i][j][r];
                }
            }
        }
    }
    #undef STAGE_A
    #undef STAGE_B
}

// ---------------------------------------------------------------------------
extern "C" void kernel_launch(void* const* d_in, const int* in_sizes, int n_in,
                              void* d_out, int out_size, void* d_ws, size_t ws_size,
                              hipStream_t stream)
{
    const float* tok = (const float*)d_in[0];
    const float* Wg  = (const float*)d_in[1];
    const float* W1  = (const float*)d_in[2];
    const float* W2  = (const float*)d_in[3];
    float* out = (float*)d_out;
    char* ws = (char*)d_ws;

    // workspace layout (bytes)
    unsigned short* W1T = (unsigned short*)(ws);                    // [E][DFF][D] bf16  67108864
    unsigned short* W2T = (unsigned short*)(ws + 67108864);         // [E][D][DFF] bf16  67108864
    unsigned short* X   = (unsigned short*)(ws + 134217728);        // [E][M][D]  bf16   41943040
    unsigned short* H   = (unsigned short*)(ws + 176160768);        // [E][M][DFF] bf16 167772160
    int*   tfs  = (int*)(ws + 343932928);                           // [E][M]            81920
    int*   eidx = (int*)(ws + 344014848);                           // [T]               65536
    float* gate = (float*)(ws + 344080384);                         // [T]               65536

    hipMemsetAsync(d_out, 0, (size_t)out_size * 4, stream);
    hipMemsetAsync(tfs, 0xFF, Eq * Mq * 4, stream);

    route_kernel<<<Tq / 4, 256, 0, stream>>>(tok, Wg, eidx, gate);
    slot_kernel<<<Bq * Eq, 64, 0, stream>>>(eidx, tfs);
    dispatch_kernel<<<Eq * Mq, 128, 0, stream>>>(tok, tfs, X);
    transpose_cvt<<<dim3(DFFq / 32, Dq / 32, Eq), 256, 0, stream>>>(W1, W1T, Dq, DFFq);
    transpose_cvt<<<dim3(Dq / 32, DFFq / 32, Eq), 256, 0, stream>>>(W2, W2T, DFFq, Dq);

    // GEMM1: H = relu(X @ W1), per-expert M=2560, N=4096, K=1024 -> 2560 blocks
    gemm3<0, DFFq, Dq><<<(Mq / 256) * (DFFq / 128) * Eq, 512, 0, stream>>>(
        X, W1T, H, nullptr, nullptr, nullptr);
    // GEMM2: out[token] += gate * (H @ W2), per-expert M=2560, N=1024, K=4096 -> 640 blocks
    gemm3<1, Dq, DFFq><<<(Mq / 256) * (Dq / 128) * Eq, 512, 0, stream>>>(
        H, W2T, nullptr, out, tfs, gate);
}

// Round 3
// 572.803 us; speedup vs baseline: 1.2764x; 1.2764x over previous
//
#include <hip/hip_runtime.h>

// MoE switch layer: B=8, N=2048, D=1024, E=8, DFF=4096, CAP=320
#define Bq 8
#define Nq 2048
#define Dq 1024
#define Eq 8
#define DFFq 4096
#define CAPq 320
#define Mq (Bq * CAPq)   // 2560 rows per expert
#define Tq (Bq * Nq)     // 16384 tokens

typedef __attribute__((ext_vector_type(8))) short bf16x8;
typedef __attribute__((ext_vector_type(4))) float f32x4;

static __device__ __forceinline__ unsigned short f2bf(float f) {
    union { float f; unsigned u; } v;
    v.f = f;
    unsigned r = v.u + 0x7fffu + ((v.u >> 16) & 1u);   // RNE
    return (unsigned short)(r >> 16);
}

static __device__ __forceinline__ void gload_lds16(const void* g, void* l) {
    __builtin_amdgcn_global_load_lds(
        (const __attribute__((address_space(1))) unsigned int*)g,
        (__attribute__((address_space(3))) unsigned int*)l, 16, 0, 0);
}

// ---------------- routing: logits -> softmax -> argmax/gate ----------------
__global__ __launch_bounds__(256) void route_kernel(
    const float* __restrict__ tok, const float* __restrict__ Wg,
    int* __restrict__ eidx, float* __restrict__ gate)
{
    int wv = threadIdx.x >> 6, lane = threadIdx.x & 63;
    int t = blockIdx.x * 4 + wv;
    const float* tp = tok + (size_t)t * Dq;
    float acc[8] = {0.f,0.f,0.f,0.f,0.f,0.f,0.f,0.f};
    for (int it = 0; it < Dq / 64; ++it) {
        int d = it * 64 + lane;
        float x = tp[d];
        const float4* w = (const float4*)(Wg + (size_t)d * 8);
        float4 w0 = w[0], w1 = w[1];
        acc[0] += x * w0.x; acc[1] += x * w0.y; acc[2] += x * w0.z; acc[3] += x * w0.w;
        acc[4] += x * w1.x; acc[5] += x * w1.y; acc[6] += x * w1.z; acc[7] += x * w1.w;
    }
#pragma unroll
    for (int e = 0; e < 8; ++e)
#pragma unroll
        for (int off = 32; off; off >>= 1)
            acc[e] += __shfl_xor(acc[e], off, 64);
    if (lane == 0) {
        float m = acc[0]; int bi = 0;
#pragma unroll
        for (int e = 1; e < 8; ++e) if (acc[e] > m) { m = acc[e]; bi = e; }
        float s = 0.f;
#pragma unroll
        for (int e = 0; e < 8; ++e) s += expf(acc[e] - m);
        eidx[t] = bi;
        gate[t] = 1.0f / s;   // max prob
    }
}

// ------------- slot assignment: cumsum-order scan per (b,e) ----------------
__global__ __launch_bounds__(64) void slot_kernel(
    const int* __restrict__ eidx, int* __restrict__ tfs)
{
    int b = blockIdx.x >> 3, e = blockIdx.x & 7;
    int lane = threadIdx.x;
    const int* ip = eidx + (size_t)b * Nq;
    int base = (e * Bq + b) * CAPq;
    int cnt = 0;
    for (int it = 0; it < Nq / 64; ++it) {
        int n = it * 64 + lane;
        bool my = (ip[n] == e);
        unsigned long long mask = __ballot(my);
        if (my) {
            int pos = cnt + __popcll(mask & ((1ull << lane) - 1ull));
            if (pos < CAPq) tfs[base + pos] = b * Nq + n;
        }
        cnt += __popcll(mask);
    }
}

// ------------- dispatch: gather token rows -> bf16 expert buffers ----------
__global__ __launch_bounds__(128) void dispatch_kernel(
    const float* __restrict__ tok, const int* __restrict__ tfs,
    unsigned short* __restrict__ X)
{
    int r = blockIdx.x;          // 0 .. E*B*CAP-1
    int t = tfs[r];
    int d0 = threadIdx.x * 8;
    unsigned short o[8];
    if (t < 0) {
#pragma unroll
        for (int k = 0; k < 8; ++k) o[k] = 0;
    } else {
        const float4* p = (const float4*)(tok + (size_t)t * Dq + d0);
        float4 a = p[0], b = p[1];
        o[0]=f2bf(a.x); o[1]=f2bf(a.y); o[2]=f2bf(a.z); o[3]=f2bf(a.w);
        o[4]=f2bf(b.x); o[5]=f2bf(b.y); o[6]=f2bf(b.z); o[7]=f2bf(b.w);
    }
    *(uint4*)(X + (size_t)r * Dq + d0) = *(const uint4*)o;
}

// ------- weight transpose+convert: in [E][R][C] f32 -> out [E][C][R] bf16 --
__global__ __launch_bounds__(256) void transpose_cvt(
    const float* __restrict__ in, unsigned short* __restrict__ out,
    int R, int C)
{
    __shared__ float tile[32][33];
    int e = blockIdx.z;
    int c0 = blockIdx.x * 32, r0 = blockIdx.y * 32;
    int tx = threadIdx.x & 31, ty = threadIdx.x >> 5;
    const float* ip = in + (size_t)e * R * C;
#pragma unroll
    for (int rr = 0; rr < 4; ++rr)
        tile[ty + rr * 8][tx] = ip[(size_t)(r0 + ty + rr * 8) * C + c0 + tx];
    __syncthreads();
    unsigned short* op = out + (size_t)e * R * C;
#pragma unroll
    for (int rr = 0; rr < 4; ++rr)
        op[(size_t)(c0 + ty + rr * 8) * R + r0 + tx] = f2bf(tile[tx][ty + rr * 8]);
}

// ======================= 8-phase 256x256 NT GEMM ===========================
// C[M][N] = A[M][K] * Bt[N][K]^T, per-expert. BM=BN=256, BK=64, 512 thr
// (8 waves = 2M x 4N, per-wave 128x64). 2 dbuf x 2 halves per operand,
// 128 KiB LDS. Counted vmcnt(4) at phases 4/8 only. XOR-swizzled LDS
// (pre-swizzled global source, linear gload_lds dest).
// MODE 0: H = relu(C) bf16.  MODE 1: scatter rows to Out with gate.
template <int MODE, int Ndim, int Kdim>
__global__ __launch_bounds__(512, 2) void gemm8p(
    const unsigned short* __restrict__ A,   // [E][M][K] bf16
    const unsigned short* __restrict__ Bt,  // [E][N][K] bf16
    unsigned short* __restrict__ Hout,      // [E][M][N] bf16  (MODE 0)
    float* __restrict__ Out,                // [T][D] f32      (MODE 1)
    const int* __restrict__ tfs,            // [E][M]
    const float* __restrict__ gate)         // [T]
{
    constexpr int NKT = Kdim / 64;           // K-tiles
    constexpr int NI  = NKT / 2;             // iterations (2 K-tiles each)
    constexpr int NTB = Ndim / 256;
    constexpr int MT  = Mq / 256;            // 10
    constexpr int NWG = MT * NTB * Eq;       // multiple of 8

    __shared__ __align__(16) unsigned short As[2 * 2 * 128 * 64];  // 64 KiB
    __shared__ __align__(16) unsigned short Bs[2 * 2 * 128 * 64];  // 64 KiB
    __shared__ int   t_lds[256];
    __shared__ float g_lds[256];

    // XCD-aware bijective swizzle (NWG % 8 == 0)
    int flat = blockIdx.x;
    int wg = (flat & 7) * (NWG / 8) + (flat >> 3);
    int e   = wg / (MT * NTB);
    int rem = wg - e * (MT * NTB);
    int mb = rem / NTB, nb = rem - mb * NTB;
    int m0 = mb * 256, n0 = nb * 256;

    const char* Ae = (const char*)(A  + (size_t)e * Mq * Kdim + (size_t)m0 * Kdim);
    const char* Be = (const char*)(Bt + (size_t)e * Ndim * Kdim + (size_t)n0 * Kdim);

    const int tid = threadIdx.x;
    if (MODE == 1 && tid < 256) {
        int t = tfs[e * Mq + m0 + tid];
        t_lds[tid] = t;
        g_lds[tid] = (t >= 0) ? gate[t] : 0.f;
    }
    __syncthreads();   // publish t_lds/g_lds; drains their loads before staging

    const int lane = tid & 63;
    const int wv = tid >> 6;
    const int wr = wv & 1, wc = wv >> 1;     // 2M x 4N waves
    const int lrow = lane & 15;
    const int lk = lane >> 4;
    const int swz = (lane & 7) << 4;

    // staging: per half-tile (128 rows x 64 cols bf16) = 2 gload_lds16/thread
    const int sk = ((tid & 7) << 4) ^ (((tid >> 3) & 7) << 4);   // pre-swizzled src
    const size_t Kb = (size_t)Kdim * 2;                           // row bytes
    const char* gA = Ae + (size_t)(tid >> 3) * Kb + sk;
    const char* gB = Be + (size_t)(tid >> 3) * Kb + sk;
    const int ldst = wv << 10;                                    // wave-uniform

    #define STG(gbase, lds, buf, h, kt) {                                      \
        const char* _g = (gbase) + (size_t)((h) * 128) * Kb + (size_t)(kt) * 128; \
        char* _l = (char*)(lds) + ((buf) * 2 + (h)) * 16384 + ldst;             \
        gload_lds16(_g,                   _l);                                  \
        gload_lds16(_g + (size_t)64 * Kb, _l + 8192); }

    bf16x8 aq[4][2];      // A frags, current mi-half
    bf16x8 bq[2][2][2];   // B frags [nj][j][kk], held across K-tile
    f32x4  acc[2][2][4][2] = {};   // [mi][nj][i][j]

    #define LDA(buf, mi) {                                                      \
        const char* _p = (const char*)As + ((buf) * 2 + (mi)) * 16384;          \
        _Pragma("unroll")                                                       \
        for (int i = 0; i < 4; ++i) {                                           \
            int rh = wr * 64 + i * 16 + lrow;                                   \
            aq[i][0] = *(const bf16x8*)(_p + rh * 128 + ((lk * 16) ^ swz));     \
            aq[i][1] = *(const bf16x8*)(_p + rh * 128 + ((64 + lk * 16) ^ swz)); } }

    #define LDB(buf, nj) {                                                      \
        const char* _p = (const char*)Bs + ((buf) * 2 + (nj)) * 16384;          \
        _Pragma("unroll")                                                       \
        for (int j = 0; j < 2; ++j) {                                           \
            int rh = wc * 32 + j * 16 + lrow;                                   \
            bq[nj][j][0] = *(const bf16x8*)(_p + rh * 128 + ((lk * 16) ^ swz)); \
            bq[nj][j][1] = *(const bf16x8*)(_p + rh * 128 + ((64 + lk * 16) ^ swz)); } }

    #define MM(mi, nj)                                                          \
        _Pragma("unroll")                                                       \
        for (int i = 0; i < 4; ++i)                                             \
        _Pragma("unroll")                                                       \
        for (int j = 0; j < 2; ++j)                                             \
        _Pragma("unroll")                                                       \
        for (int kk = 0; kk < 2; ++kk)                                          \
            acc[mi][nj][i][j] = __builtin_amdgcn_mfma_f32_16x16x32_bf16(        \
                aq[i][kk], bq[nj][j][kk], acc[mi][nj][i][j], 0, 0, 0);

    #define PH_BAR() { __builtin_amdgcn_s_barrier(); __builtin_amdgcn_sched_barrier(0); }
    #define LGKM0()  { asm volatile("s_waitcnt lgkmcnt(0)"); __builtin_amdgcn_sched_barrier(0); }
    #define PRIO_MM(mi, nj) { __builtin_amdgcn_s_setprio(1); MM(mi, nj); __builtin_amdgcn_s_setprio(0); }

    // prologue: tile0 (buf0, all 4 halves) + tile1 (buf1, h0 of A and B)
    STG(gA, As, 0, 0, 0);
    STG(gB, Bs, 0, 0, 0);
    STG(gA, As, 0, 1, 0);
    STG(gB, Bs, 0, 1, 0);
    STG(gA, As, 1, 0, 1);
    STG(gB, Bs, 1, 0, 1);
    asm volatile("s_waitcnt vmcnt(4)");   // tile0 fully resident, tile1 in flight
    PH_BAR();

    for (int u = 0; u < NI; ++u) {
        const int kt0 = 2 * u, kt1 = 2 * u + 1;
        const bool lastI = (u == NI - 1);

        // ph0: Q(buf0, mi0, nj0); stage A.buf1.h1 <- kt1
        LDA(0, 0); LDB(0, 0);
        STG(gA, As, 1, 1, kt1);
        PH_BAR(); LGKM0(); PRIO_MM(0, 0); PH_BAR();

        // ph1: Q(buf0, mi0, nj1); stage B.buf1.h1 <- kt1
        LDB(0, 1);
        STG(gB, Bs, 1, 1, kt1);
        PH_BAR(); LGKM0(); PRIO_MM(0, 1); PH_BAR();

        // ph2: Q(buf0, mi1, nj0); stage A.buf0.h0 <- kt0+2
        LDA(0, 1);
        if (!lastI) STG(gA, As, 0, 0, kt0 + 2);
        PH_BAR(); LGKM0(); PRIO_MM(1, 0); PH_BAR();

        // ph3: Q(buf0, mi1, nj1); stage B.buf0.h0 <- kt0+2; K-tile boundary wait
        if (!lastI) STG(gB, Bs, 0, 0, kt0 + 2);
        PH_BAR(); LGKM0(); PRIO_MM(1, 1);
        if (lastI) { asm volatile("s_waitcnt vmcnt(0)"); }
        else       { asm volatile("s_waitcnt vmcnt(4)"); }
        PH_BAR();

        // ph4: Q(buf1, mi0, nj0); stage A.buf0.h1 <- kt0+2
        LDA(1, 0); LDB(1, 0);
        if (!lastI) STG(gA, As, 0, 1, kt0 + 2);
        PH_BAR(); LGKM0(); PRIO_MM(0, 0); PH_BAR();

        // ph5: Q(buf1, mi0, nj1); stage B.buf0.h1 <- kt0+2
        LDB(1, 1);
        if (!lastI) STG(gB, Bs, 0, 1, kt0 + 2);
        PH_BAR(); LGKM0(); PRIO_MM(0, 1); PH_BAR();

        // ph6: Q(buf1, mi1, nj0); stage A.buf1.h0 <- kt1+2
        LDA(1, 1);
        if (!lastI) STG(gA, As, 1, 0, kt1 + 2);
        PH_BAR(); LGKM0(); PRIO_MM(1, 0); PH_BAR();

        // ph7: Q(buf1, mi1, nj1); stage B.buf1.h0 <- kt1+2; iter boundary wait
        if (!lastI) STG(gB, Bs, 1, 0, kt1 + 2);
        PH_BAR(); LGKM0(); PRIO_MM(1, 1);
        if (!lastI) {
            asm volatile("s_waitcnt vmcnt(4)");
            PH_BAR();
        }
    }

    // -------------------------------- epilogue --------------------------------
    if (MODE == 0) {
        unsigned short* Hp = Hout + (size_t)e * Mq * Ndim;
#pragma unroll
        for (int mi = 0; mi < 2; ++mi)
#pragma unroll
        for (int nj = 0; nj < 2; ++nj)
#pragma unroll
        for (int i = 0; i < 4; ++i) {
            int row = m0 + mi * 128 + wr * 64 + i * 16 + lk * 4;
#pragma unroll
            for (int j = 0; j < 2; ++j) {
                int col = n0 + nj * 128 + wc * 32 + j * 16 + lrow;
#pragma unroll
                for (int r = 0; r < 4; ++r)
                    Hp[(size_t)(row + r) * Ndim + col] =
                        f2bf(fmaxf(acc[mi][nj][i][j][r], 0.f));
            }
        }
    } else {
#pragma unroll
        for (int mi = 0; mi < 2; ++mi)
#pragma unroll
        for (int i = 0; i < 4; ++i) {
            int rl = mi * 128 + wr * 64 + i * 16 + lk * 4;
#pragma unroll
            for (int r = 0; r < 4; ++r) {
                int tt = t_lds[rl + r];
                if (tt < 0) continue;
                float g = g_lds[rl + r];
#pragma unroll
                for (int nj = 0; nj < 2; ++nj)
#pragma unroll
                for (int j = 0; j < 2; ++j) {
                    int col = n0 + nj * 128 + wc * 32 + j * 16 + lrow;
                    Out[(size_t)tt * Dq + col] = g * acc[mi][nj][i][j][r];
                }
            }
        }
    }
    #undef STG
    #undef LDA
    #undef LDB
    #undef MM
    #undef PH_BAR
    #undef LGKM0
    #undef PRIO_MM
}

// ---------------------------------------------------------------------------
extern "C" void kernel_launch(void* const* d_in, const int* in_sizes, int n_in,
                              void* d_out, int out_size, void* d_ws, size_t ws_size,
                              hipStream_t stream)
{
    const float* tok = (const float*)d_in[0];
    const float* Wg  = (const float*)d_in[1];
    const float* W1  = (const float*)d_in[2];
    const float* W2  = (const float*)d_in[3];
    float* out = (float*)d_out;
    char* ws = (char*)d_ws;

    // workspace layout (bytes)
    unsigned short* W1T = (unsigned short*)(ws);                    // [E][DFF][D] bf16  67108864
    unsigned short* W2T = (unsigned short*)(ws + 67108864);         // [E][D][DFF] bf16  67108864
    unsigned short* X   = (unsigned short*)(ws + 134217728);        // [E][M][D]  bf16   41943040
    unsigned short* H   = (unsigned short*)(ws + 176160768);        // [E][M][DFF] bf16 167772160
    int*   tfs  = (int*)(ws + 343932928);                           // [E][M]            81920
    int*   eidx = (int*)(ws + 344014848);                           // [T]               65536
    float* gate = (float*)(ws + 344080384);                         // [T]               65536

    hipMemsetAsync(d_out, 0, (size_t)out_size * 4, stream);
    hipMemsetAsync(tfs, 0xFF, Eq * Mq * 4, stream);

    route_kernel<<<Tq / 4, 256, 0, stream>>>(tok, Wg, eidx, gate);
    slot_kernel<<<Bq * Eq, 64, 0, stream>>>(eidx, tfs);
    dispatch_kernel<<<Eq * Mq, 128, 0, stream>>>(tok, tfs, X);
    transpose_cvt<<<dim3(DFFq / 32, Dq / 32, Eq), 256, 0, stream>>>(W1, W1T, Dq, DFFq);
    transpose_cvt<<<dim3(Dq / 32, DFFq / 32, Eq), 256, 0, stream>>>(W2, W2T, DFFq, Dq);

    // GEMM1: H = relu(X @ W1), per-expert M=2560, N=4096, K=1024 -> 1280 blocks
    gemm8p<0, DFFq, Dq><<<(Mq / 256) * (DFFq / 256) * Eq, 512, 0, stream>>>(
        X, W1T, H, nullptr, nullptr, nullptr);
    // GEMM2: out[token] = gate * (H @ W2), per-expert M=2560, N=1024, K=4096 -> 320 blocks
    gemm8p<1, Dq, DFFq><<<(Mq / 256) * (Dq / 256) * Eq, 512, 0, stream>>>(
        H, W2T, nullptr, out, tfs, gate);
}

// Round 4
// 562.328 us; speedup vs baseline: 1.3002x; 1.0186x over previous
//
#include <hip/hip_runtime.h>

// MoE switch layer: B=8, N=2048, D=1024, E=8, DFF=4096, CAP=320
#define Bq 8
#define Nq 2048
#define Dq 1024
#define Eq 8
#define DFFq 4096
#define CAPq 320
#define Mq (Bq * CAPq)   // 2560 rows per expert
#define Tq (Bq * Nq)     // 16384 tokens

typedef __attribute__((ext_vector_type(8))) short bf16x8;
typedef __attribute__((ext_vector_type(4))) float f32x4;

static __device__ __forceinline__ unsigned short f2bf(float f) {
    union { float f; unsigned u; } v;
    v.f = f;
    unsigned r = v.u + 0x7fffu + ((v.u >> 16) & 1u);   // RNE
    return (unsigned short)(r >> 16);
}

static __device__ __forceinline__ void gload_lds16(const void* g, void* l) {
    __builtin_amdgcn_global_load_lds(
        (const __attribute__((address_space(1))) unsigned int*)g,
        (__attribute__((address_space(3))) unsigned int*)l, 16, 0, 0);
}

// ---------------- routing: logits -> softmax -> argmax/gate ----------------
__global__ __launch_bounds__(256) void route_kernel(
    const float* __restrict__ tok, const float* __restrict__ Wg,
    int* __restrict__ eidx, float* __restrict__ gate)
{
    int wv = threadIdx.x >> 6, lane = threadIdx.x & 63;
    int t = blockIdx.x * 4 + wv;
    const float* tp = tok + (size_t)t * Dq;
    float acc[8] = {0.f,0.f,0.f,0.f,0.f,0.f,0.f,0.f};
    for (int it = 0; it < Dq / 64; ++it) {
        int d = it * 64 + lane;
        float x = tp[d];
        const float4* w = (const float4*)(Wg + (size_t)d * 8);
        float4 w0 = w[0], w1 = w[1];
        acc[0] += x * w0.x; acc[1] += x * w0.y; acc[2] += x * w0.z; acc[3] += x * w0.w;
        acc[4] += x * w1.x; acc[5] += x * w1.y; acc[6] += x * w1.z; acc[7] += x * w1.w;
    }
#pragma unroll
    for (int e = 0; e < 8; ++e)
#pragma unroll
        for (int off = 32; off; off >>= 1)
            acc[e] += __shfl_xor(acc[e], off, 64);
    if (lane == 0) {
        float m = acc[0]; int bi = 0;
#pragma unroll
        for (int e = 1; e < 8; ++e) if (acc[e] > m) { m = acc[e]; bi = e; }
        float s = 0.f;
#pragma unroll
        for (int e = 0; e < 8; ++e) s += expf(acc[e] - m);
        eidx[t] = bi;
        gate[t] = 1.0f / s;   // max prob
    }
}

// ------------- slot assignment: cumsum-order scan per (b,e) ----------------
__global__ __launch_bounds__(64) void slot_kernel(
    const int* __restrict__ eidx, int* __restrict__ tfs)
{
    int b = blockIdx.x >> 3, e = blockIdx.x & 7;
    int lane = threadIdx.x;
    const int* ip = eidx + (size_t)b * Nq;
    int base = (e * Bq + b) * CAPq;
    int cnt = 0;
    for (int it = 0; it < Nq / 64; ++it) {
        int n = it * 64 + lane;
        bool my = (ip[n] == e);
        unsigned long long mask = __ballot(my);
        if (my) {
            int pos = cnt + __popcll(mask & ((1ull << lane) - 1ull));
            if (pos < CAPq) tfs[base + pos] = b * Nq + n;
        }
        cnt += __popcll(mask);
    }
}

// ------------- dispatch: gather token rows -> bf16 expert buffers ----------
__global__ __launch_bounds__(128) void dispatch_kernel(
    const float* __restrict__ tok, const int* __restrict__ tfs,
    unsigned short* __restrict__ X)
{
    int r = blockIdx.x;          // 0 .. E*B*CAP-1
    int t = tfs[r];
    int d0 = threadIdx.x * 8;
    unsigned short o[8];
    if (t < 0) {
#pragma unroll
        for (int k = 0; k < 8; ++k) o[k] = 0;
    } else {
        const float4* p = (const float4*)(tok + (size_t)t * Dq + d0);
        float4 a = p[0], b = p[1];
        o[0]=f2bf(a.x); o[1]=f2bf(a.y); o[2]=f2bf(a.z); o[3]=f2bf(a.w);
        o[4]=f2bf(b.x); o[5]=f2bf(b.y); o[6]=f2bf(b.z); o[7]=f2bf(b.w);
    }
    *(uint4*)(X + (size_t)r * Dq + d0) = *(const uint4*)o;
}

// ------- weight transpose+convert: in [E][R][C] f32 -> out [E][C][R] bf16 --
__global__ __launch_bounds__(256) void transpose_cvt(
    const float* __restrict__ in, unsigned short* __restrict__ out,
    int R, int C)
{
    __shared__ float tile[32][33];
    int e = blockIdx.z;
    int c0 = blockIdx.x * 32, r0 = blockIdx.y * 32;
    int tx = threadIdx.x & 31, ty = threadIdx.x >> 5;
    const float* ip = in + (size_t)e * R * C;
#pragma unroll
    for (int rr = 0; rr < 4; ++rr)
        tile[ty + rr * 8][tx] = ip[(size_t)(r0 + ty + rr * 8) * C + c0 + tx];
    __syncthreads();
    unsigned short* op = out + (size_t)e * R * C;
#pragma unroll
    for (int rr = 0; rr < 4; ++rr)
        op[(size_t)(c0 + ty + rr * 8) * R + r0 + tx] = f2bf(tile[tx][ty + rr * 8]);
}

// ================= 8-phase 256x256 NT GEMM, pipelined LDS reads ============
// C[M][N] = A[M][K] * Bt[N][K]^T, per-expert. BM=BN=256, BK=64, 512 thr
// (8 waves = 2M x 4N, per-wave 128x64). ds_reads issued ONE PHASE AHEAD:
// B-frags at phase top (no WAR), A-frags after the MFMA burst (register
// time-share, WAR-safe by program order). Compiler emits counted lgkm waits.
// Staging: 1 half-tile per phase, vmcnt(4) at 6/8 phase ends (each read's
// region staged >=2.5 phases earlier). XOR-swizzled LDS as before.
// MODE 0: H = relu(C) bf16.  MODE 1: scatter rows to Out with gate.
template <int MODE, int Ndim, int Kdim>
__global__ __launch_bounds__(512, 2) void gemm8p(
    const unsigned short* __restrict__ A,   // [E][M][K] bf16
    const unsigned short* __restrict__ Bt,  // [E][N][K] bf16
    unsigned short* __restrict__ Hout,      // [E][M][N] bf16  (MODE 0)
    float* __restrict__ Out,                // [T][D] f32      (MODE 1)
    const int* __restrict__ tfs,            // [E][M]
    const float* __restrict__ gate)         // [T]
{
    constexpr int NKT = Kdim / 64;           // K-tiles
    constexpr int NI  = NKT / 2;             // iterations (2 K-tiles each)
    constexpr int NTB = Ndim / 256;
    constexpr int MT  = Mq / 256;            // 10
    constexpr int NWG = MT * NTB * Eq;       // multiple of 8

    __shared__ __align__(16) unsigned short As[2 * 2 * 128 * 64];  // 64 KiB
    __shared__ __align__(16) unsigned short Bs[2 * 2 * 128 * 64];  // 64 KiB
    __shared__ int   t_lds[256];
    __shared__ float g_lds[256];

    // XCD-aware bijective swizzle (NWG % 8 == 0)
    int flat = blockIdx.x;
    int wg = (flat & 7) * (NWG / 8) + (flat >> 3);
    int e   = wg / (MT * NTB);
    int rem = wg - e * (MT * NTB);
    int mb = rem / NTB, nb = rem - mb * NTB;
    int m0 = mb * 256, n0 = nb * 256;

    const char* Ae = (const char*)(A  + (size_t)e * Mq * Kdim + (size_t)m0 * Kdim);
    const char* Be = (const char*)(Bt + (size_t)e * Ndim * Kdim + (size_t)n0 * Kdim);

    const int tid = threadIdx.x;
    if (MODE == 1 && tid < 256) {
        int t = tfs[e * Mq + m0 + tid];
        t_lds[tid] = t;
        g_lds[tid] = (t >= 0) ? gate[t] : 0.f;
    }
    __syncthreads();   // publish t_lds/g_lds before staging begins

    const int lane = tid & 63;
    const int wv = tid >> 6;
    const int wr = wv & 1, wc = wv >> 1;     // 2M x 4N waves
    const int lrow = lane & 15;
    const int lk = lane >> 4;
    const int swz = (lane & 7) << 4;

    // staging: per half-tile (128 rows x 64 cols bf16) = 2 gload_lds16/thread
    const int sk = ((tid & 7) << 4) ^ (((tid >> 3) & 7) << 4);   // pre-swizzled src
    const size_t Kb = (size_t)Kdim * 2;                           // row bytes
    const char* gA = Ae + (size_t)(tid >> 3) * Kb + sk;
    const char* gB = Be + (size_t)(tid >> 3) * Kb + sk;
    const int ldst = wv << 10;                                    // wave-uniform

    #define STG(gbase, lds, buf, h, kt) {                                       \
        const char* _g = (gbase) + (size_t)((h) * 128) * Kb + (size_t)(kt) * 128; \
        char* _l = (char*)(lds) + ((buf) * 2 + (h)) * 16384 + ldst;              \
        gload_lds16(_g,                   _l);                                   \
        gload_lds16(_g + (size_t)64 * Kb, _l + 8192); }

    bf16x8 aq[4][2];                 // A frags (time-shared across phases)
    bf16x8 bq0[2][2], bq1[2][2];     // B frags, two sets
    f32x4  acc[2][2][4][2] = {};     // [mi][nj][i][j]

    #define LDA(buf, mi) {                                                      \
        const char* _p = (const char*)As + ((buf) * 2 + (mi)) * 16384;          \
        _Pragma("unroll")                                                       \
        for (int i = 0; i < 4; ++i) {                                           \
            int rh = wr * 64 + i * 16 + lrow;                                   \
            aq[i][0] = *(const bf16x8*)(_p + rh * 128 + ((lk * 16) ^ swz));     \
            aq[i][1] = *(const bf16x8*)(_p + rh * 128 + ((64 + lk * 16) ^ swz)); } }

    #define LDB(bqz, buf, h) {                                                  \
        const char* _p = (const char*)Bs + ((buf) * 2 + (h)) * 16384;           \
        _Pragma("unroll")                                                       \
        for (int j = 0; j < 2; ++j) {                                           \
            int rh = wc * 32 + j * 16 + lrow;                                   \
            bqz[j][0] = *(const bf16x8*)(_p + rh * 128 + ((lk * 16) ^ swz));    \
            bqz[j][1] = *(const bf16x8*)(_p + rh * 128 + ((64 + lk * 16) ^ swz)); } }

    #define MMQ(mi, bqz, z)                                                     \
        _Pragma("unroll")                                                       \
        for (int i = 0; i < 4; ++i)                                             \
        _Pragma("unroll")                                                       \
        for (int j = 0; j < 2; ++j)                                             \
        _Pragma("unroll")                                                       \
        for (int kk = 0; kk < 2; ++kk)                                          \
            acc[mi][z][i][j] = __builtin_amdgcn_mfma_f32_16x16x32_bf16(         \
                aq[i][kk], bqz[j][kk], acc[mi][z][i][j], 0, 0, 0);

    #define SB __builtin_amdgcn_sched_barrier(0)
    #define BAR { __builtin_amdgcn_s_barrier(); SB; }
    #define VM(n) { asm volatile("s_waitcnt vmcnt(" #n ")"); SB; }
    #define P1 __builtin_amdgcn_s_setprio(1)
    #define P0 __builtin_amdgcn_s_setprio(0)

    // ---- prologue: stage b0 (4 half-tiles) + A.b1.h0; first reads ----
    STG(gA, As, 0, 0, 0);
    STG(gB, Bs, 0, 0, 0);
    STG(gB, Bs, 0, 1, 0);
    STG(gA, As, 0, 1, 0);
    STG(gA, As, 1, 0, 1);
    VM(6); BAR;                 // A.b0.h0 + B.b0.h0 resident
    LDB(bq0, 0, 0);
    LDA(0, 0);
    SB;
    VM(4); BAR;                 // B.b0.h1 resident (for ph0's TOPB)

    for (int u = 0; u < NI - 1; ++u) {
        const int ktb1 = 2 * u + 1, ktb0n = 2 * u + 2, ktb1n = 2 * u + 3;
        // ph0: MM(0,0)b0 | topB bq1<-B.b0.h1 | STG B.b1.h0
        LDB(bq1, 0, 1); SB;
        STG(gB, Bs, 1, 0, ktb1);
        P1; MMQ(0, bq0, 0); P0;
        VM(4); BAR;
        // ph1: MM(0,1)b0 | botA aq<-A.b0.h1 | STG B.b1.h1
        STG(gB, Bs, 1, 1, ktb1);
        P1; MMQ(0, bq1, 1); P0;
        LDA(0, 1); SB;
        BAR;
        // ph2: MM(1,0)b0 | STG A.b1.h1
        STG(gA, As, 1, 1, ktb1);
        P1; MMQ(1, bq0, 0); P0;
        VM(4); BAR;
        // ph3: MM(1,1)b0 | topB bq0<-B.b1.h0 | botA aq<-A.b1.h0 | STG A.b0'.h0
        LDB(bq0, 1, 0); SB;
        STG(gA, As, 0, 0, ktb0n);
        P1; MMQ(1, bq1, 1); P0;
        LDA(1, 0); SB;
        VM(4); BAR;
        // ph4: MM(0,0)b1 | topB bq1<-B.b1.h1 | STG B.b0'.h0
        LDB(bq1, 1, 1); SB;
        STG(gB, Bs, 0, 0, ktb0n);
        P1; MMQ(0, bq0, 0); P0;
        VM(4); BAR;
        // ph5: MM(0,1)b1 | botA aq<-A.b1.h1 | STG B.b0'.h1
        STG(gB, Bs, 0, 1, ktb0n);
        P1; MMQ(0, bq1, 1); P0;
        LDA(1, 1); SB;
        BAR;
        // ph6: MM(1,0)b1 | STG A.b0'.h1
        STG(gA, As, 0, 1, ktb0n);
        P1; MMQ(1, bq0, 0); P0;
        VM(4); BAR;
        // ph7: MM(1,1)b1 | topB bq0<-B.b0'.h0 | botA aq<-A.b0'.h0 | STG A.b1'.h0
        LDB(bq0, 0, 0); SB;
        STG(gA, As, 1, 0, ktb1n);
        P1; MMQ(1, bq1, 1); P0;
        LDA(0, 0); SB;
        VM(4); BAR;
    }

    // ---- last iteration (no next-tile staging / no next reads) ----
    {
        // ph0
        LDB(bq1, 0, 1); SB;
        STG(gB, Bs, 1, 0, NKT - 1);
        P1; MMQ(0, bq0, 0); P0;
        VM(4); BAR;
        // ph1
        STG(gB, Bs, 1, 1, NKT - 1);
        P1; MMQ(0, bq1, 1); P0;
        LDA(0, 1); SB;
        BAR;
        // ph2
        STG(gA, As, 1, 1, NKT - 1);
        P1; MMQ(1, bq0, 0); P0;
        VM(4); BAR;
        // ph3 (no STG -> tighter count to retire B.b1.h1)
        LDB(bq0, 1, 0); SB;
        P1; MMQ(1, bq1, 1); P0;
        LDA(1, 0); SB;
        VM(2); BAR;
        // ph4 (retire A.b1.h1 for ph5's A-read)
        LDB(bq1, 1, 1); SB;
        P1; MMQ(0, bq0, 0); P0;
        VM(0); BAR;
        // ph5
        P1; MMQ(0, bq1, 1); P0;
        LDA(1, 1); SB;
        // ph6
        P1; MMQ(1, bq0, 0); P0;
        // ph7
        P1; MMQ(1, bq1, 1); P0;
    }

    // -------------------------------- epilogue --------------------------------
    if (MODE == 0) {
        unsigned short* Hp = Hout + (size_t)e * Mq * Ndim;
#pragma unroll
        for (int mi = 0; mi < 2; ++mi)
#pragma unroll
        for (int nj = 0; nj < 2; ++nj)
#pragma unroll
        for (int i = 0; i < 4; ++i) {
            int row = m0 + mi * 128 + wr * 64 + i * 16 + lk * 4;
#pragma unroll
            for (int j = 0; j < 2; ++j) {
                int col = n0 + nj * 128 + wc * 32 + j * 16 + lrow;
#pragma unroll
                for (int r = 0; r < 4; ++r)
                    Hp[(size_t)(row + r) * Ndim + col] =
                        f2bf(fmaxf(acc[mi][nj][i][j][r], 0.f));
            }
        }
    } else {
#pragma unroll
        for (int mi = 0; mi < 2; ++mi)
#pragma unroll
        for (int i = 0; i < 4; ++i) {
            int rl = mi * 128 + wr * 64 + i * 16 + lk * 4;
#pragma unroll
            for (int r = 0; r < 4; ++r) {
                int tt = t_lds[rl + r];
                if (tt < 0) continue;
                float g = g_lds[rl + r];
#pragma unroll
                for (int nj = 0; nj < 2; ++nj)
#pragma unroll
                for (int j = 0; j < 2; ++j) {
                    int col = n0 + nj * 128 + wc * 32 + j * 16 + lrow;
                    Out[(size_t)tt * Dq + col] = g * acc[mi][nj][i][j][r];
                }
            }
        }
    }
    #undef STG
    #undef LDA
    #undef LDB
    #undef MMQ
    #undef SB
    #undef BAR
    #undef VM
    #undef P1
    #undef P0
}

// ---------------------------------------------------------------------------
extern "C" void kernel_launch(void* const* d_in, const int* in_sizes, int n_in,
                              void* d_out, int out_size, void* d_ws, size_t ws_size,
                              hipStream_t stream)
{
    const float* tok = (const float*)d_in[0];
    const float* Wg  = (const float*)d_in[1];
    const float* W1  = (const float*)d_in[2];
    const float* W2  = (const float*)d_in[3];
    float* out = (float*)d_out;
    char* ws = (char*)d_ws;

    // workspace layout (bytes)
    unsigned short* W1T = (unsigned short*)(ws);                    // [E][DFF][D] bf16  67108864
    unsigned short* W2T = (unsigned short*)(ws + 67108864);         // [E][D][DFF] bf16  67108864
    unsigned short* X   = (unsigned short*)(ws + 134217728);        // [E][M][D]  bf16   41943040
    unsigned short* H   = (unsigned short*)(ws + 176160768);        // [E][M][DFF] bf16 167772160
    int*   tfs  = (int*)(ws + 343932928);                           // [E][M]            81920
    int*   eidx = (int*)(ws + 344014848);                           // [T]               65536
    float* gate = (float*)(ws + 344080384);                         // [T]               65536

    hipMemsetAsync(d_out, 0, (size_t)out_size * 4, stream);
    hipMemsetAsync(tfs, 0xFF, Eq * Mq * 4, stream);

    route_kernel<<<Tq / 4, 256, 0, stream>>>(tok, Wg, eidx, gate);
    slot_kernel<<<Bq * Eq, 64, 0, stream>>>(eidx, tfs);
    dispatch_kernel<<<Eq * Mq, 128, 0, stream>>>(tok, tfs, X);
    transpose_cvt<<<dim3(DFFq / 32, Dq / 32, Eq), 256, 0, stream>>>(W1, W1T, Dq, DFFq);
    transpose_cvt<<<dim3(Dq / 32, DFFq / 32, Eq), 256, 0, stream>>>(W2, W2T, DFFq, Dq);

    // GEMM1: H = relu(X @ W1), per-expert M=2560, N=4096, K=1024 -> 1280 blocks
    gemm8p<0, DFFq, Dq><<<(Mq / 256) * (DFFq / 256) * Eq, 512, 0, stream>>>(
        X, W1T, H, nullptr, nullptr, nullptr);
    // GEMM2: out[token] = gate * (H @ W2), per-expert M=2560, N=1024, K=4096 -> 320 blocks
    gemm8p<1, Dq, DFFq><<<(Mq / 256) * (Dq / 256) * Eq, 512, 0, stream>>>(
        H, W2T, nullptr, out, tfs, gate);
}